// Round 1
// baseline (941.822 us; speedup 1.0000x reference)
//
#include <hip/hip_runtime.h>
#include <math.h>

constexpr int IN    = 256;   // input feature dim (both layers' K)
constexpr int HEADS = 4;
constexpr int HID   = 64;
constexpr int NCLS  = 47;
constexpr int HD0   = HEADS * HID;   // 256
constexpr int HD1   = HEADS * NCLS;  // 188
constexpr float NEG_SLOPE = 0.2f;

static __device__ __forceinline__ float leaky(float x) {
    return x >= 0.f ? x : NEG_SLOPE * x;
}

// v[k,h] = sum_d W[k, h*D+d] * attn[h,d]   (folds attention vector through W)
__global__ void make_v(const float* __restrict__ W, const float* __restrict__ attn,
                       float* __restrict__ v, int D) {
    int id = blockIdx.x * blockDim.x + threadIdx.x;
    if (id >= IN * HEADS) return;
    int k = id >> 2, h = id & 3;
    const float* wr = W + (size_t)k * (HEADS * D) + h * D;
    const float* ar = attn + h * D;
    float s = 0.f;
    for (int d = 0; d < D; ++d) s += wr[d] * ar[d];
    v[k * 4 + h] = s;
}

// el[m,0..3] = A[m,:] @ vl ; er[m,0..3] = A[m,:] @ vr for m < Mr. One wave per row.
__global__ __launch_bounds__(256) void gemv_lr(const float* __restrict__ A,
        const float* __restrict__ vl, const float* __restrict__ vr,
        float* __restrict__ el, float* __restrict__ er, int M, int Mr) {
    int wave = threadIdx.x >> 6;
    int lane = threadIdx.x & 63;
    int row = blockIdx.x * 4 + wave;
    if (row >= M) return;
    const float* a = A + (size_t)row * IN;
    bool do_r = row < Mr;
    float l0 = 0, l1 = 0, l2 = 0, l3 = 0;
    float r0 = 0, r1 = 0, r2 = 0, r3 = 0;
#pragma unroll
    for (int c = 0; c < 4; ++c) {
        int k = c * 64 + lane;
        float av = a[k];
        float4 vv = *(const float4*)(vl + k * 4);
        l0 += av * vv.x; l1 += av * vv.y; l2 += av * vv.z; l3 += av * vv.w;
        if (do_r) {
            float4 vw = *(const float4*)(vr + k * 4);
            r0 += av * vw.x; r1 += av * vw.y; r2 += av * vw.z; r3 += av * vw.w;
        }
    }
#pragma unroll
    for (int off = 32; off; off >>= 1) {
        l0 += __shfl_xor(l0, off); l1 += __shfl_xor(l1, off);
        l2 += __shfl_xor(l2, off); l3 += __shfl_xor(l3, off);
        r0 += __shfl_xor(r0, off); r1 += __shfl_xor(r1, off);
        r2 += __shfl_xor(r2, off); r3 += __shfl_xor(r3, off);
    }
    if (lane == 0) {
        *(float4*)(el + (size_t)row * 4) = make_float4(l0, l1, l2, l3);
        if (do_r) *(float4*)(er + (size_t)row * 4) = make_float4(r0, r1, r2, r3);
    }
}

// C[M,NCOLS] = A[M,256] @ B[256,NCOLS], fp32, 64x256 tile, 8x8 per thread.
template <int NCOLS>
__global__ __launch_bounds__(256) void gemm_f32(const float* __restrict__ A,
        const float* __restrict__ B, float* __restrict__ C, int M) {
    __shared__ float As[16][64];    // transposed: As[k][m]
    __shared__ float Bs[16][260];   // Bs[k][n], padded
    const int tid = threadIdx.x;
    const int ty = tid >> 5;        // 0..7  (8 rows each)
    const int tx = tid & 31;        // 0..31 (8 cols each)
    const int bm = blockIdx.x * 64;
    const int am = tid >> 2, ak = (tid & 3) * 4;
    const int kb = tid >> 4, nb = (tid & 15) * 16;
    const int arow = bm + am;
    float acc[8][8] = {};
    for (int k0 = 0; k0 < IN; k0 += 16) {
        float4 av = make_float4(0.f, 0.f, 0.f, 0.f);
        if (arow < M) av = *(const float4*)(A + (size_t)arow * IN + k0 + ak);
        As[ak + 0][am] = av.x; As[ak + 1][am] = av.y;
        As[ak + 2][am] = av.z; As[ak + 3][am] = av.w;
#pragma unroll
        for (int j = 0; j < 4; ++j) {
            int col = nb + j * 4;
            float4 bv = make_float4(0.f, 0.f, 0.f, 0.f);
            if (col < NCOLS) bv = *(const float4*)(B + (size_t)(k0 + kb) * NCOLS + col);
            *(float4*)&Bs[kb][col] = bv;
        }
        __syncthreads();
#pragma unroll
        for (int kk = 0; kk < 16; ++kk) {
            float4 a0 = *(const float4*)&As[kk][ty * 8];
            float4 a1 = *(const float4*)&As[kk][ty * 8 + 4];
            float4 b0 = *(const float4*)&Bs[kk][tx * 8];
            float4 b1 = *(const float4*)&Bs[kk][tx * 8 + 4];
            float a_[8] = {a0.x, a0.y, a0.z, a0.w, a1.x, a1.y, a1.z, a1.w};
            float b_[8] = {b0.x, b0.y, b0.z, b0.w, b1.x, b1.y, b1.z, b1.w};
#pragma unroll
            for (int i = 0; i < 8; ++i)
#pragma unroll
                for (int j = 0; j < 8; ++j)
                    acc[i][j] = fmaf(a_[i], b_[j], acc[i][j]);
        }
        __syncthreads();
    }
#pragma unroll
    for (int i = 0; i < 8; ++i) {
        int row = bm + ty * 8 + i;
        if (row < M) {
#pragma unroll
            for (int jq = 0; jq < 2; ++jq) {
                int col = tx * 8 + jq * 4;
                if (col < NCOLS)
                    *(float4*)(C + (size_t)row * NCOLS + col) =
                        make_float4(acc[i][jq * 4 + 0], acc[i][jq * 4 + 1],
                                    acc[i][jq * 4 + 2], acc[i][jq * 4 + 3]);
            }
        }
    }
}

__global__ void hist_k(const int* __restrict__ dst, int E, int* __restrict__ counts) {
    int i = blockIdx.x * blockDim.x + threadIdx.x;
    if (i < E) atomicAdd(&counts[dst[i]], 1);
}

__global__ __launch_bounds__(1024) void scan_k(const int* __restrict__ counts, int n,
        int* __restrict__ offsets, int* __restrict__ cursor) {
    __shared__ int part[1024];
    int tid = threadIdx.x;
    int chunk = (n + 1023) >> 10;
    int b = tid * chunk, e = min(b + chunk, n);
    int s = 0;
    for (int i = b; i < e; ++i) s += counts[i];
    part[tid] = s;
    __syncthreads();
    if (tid == 0) {
        int run = 0;
        for (int i = 0; i < 1024; ++i) { int t = part[i]; part[i] = run; run += t; }
        offsets[n] = run;
    }
    __syncthreads();
    int run = part[tid];
    for (int i = b; i < e; ++i) {
        int c = counts[i];
        offsets[i] = run;
        cursor[i] = run;
        run += c;
    }
}

__global__ void scatter_k(const int* __restrict__ src, const int* __restrict__ dst, int E,
        int* __restrict__ cursor, int* __restrict__ ssrc) {
    int i = blockIdx.x * blockDim.x + threadIdx.x;
    if (i < E) {
        int p = atomicAdd(&cursor[dst[i]], 1);
        ssrc[p] = src[i];
    }
}

// Layer-0 aggregation: one wave per dst node, D=64, H=4 -> lane owns float4 of features.
__global__ __launch_bounds__(64) void agg_l0(const int* __restrict__ ssrc,
        const int* __restrict__ offsets, const float* __restrict__ el,
        const float* __restrict__ er, const float* __restrict__ z,
        const float* __restrict__ bias, float* __restrict__ hout) {
    int d = blockIdx.x;
    int lane = threadIdx.x;
    int head = lane >> 4;
    int beg = offsets[d], end = offsets[d + 1];
    float4 er4 = *(const float4*)(er + (size_t)d * 4);
    float m0 = -INFINITY, m1 = -INFINITY, m2 = -INFINITY, m3 = -INFINITY;
    for (int j = beg + lane; j < end; j += 64) {
        int s = ssrc[j];
        float4 e4 = *(const float4*)(el + (size_t)s * 4);
        m0 = fmaxf(m0, leaky(e4.x + er4.x));
        m1 = fmaxf(m1, leaky(e4.y + er4.y));
        m2 = fmaxf(m2, leaky(e4.z + er4.z));
        m3 = fmaxf(m3, leaky(e4.w + er4.w));
    }
#pragma unroll
    for (int off = 32; off; off >>= 1) {
        m0 = fmaxf(m0, __shfl_xor(m0, off));
        m1 = fmaxf(m1, __shfl_xor(m1, off));
        m2 = fmaxf(m2, __shfl_xor(m2, off));
        m3 = fmaxf(m3, __shfl_xor(m3, off));
    }
    float mh  = head == 0 ? m0 : head == 1 ? m1 : head == 2 ? m2 : m3;
    float erh = head == 0 ? er4.x : head == 1 ? er4.y : head == 2 ? er4.z : er4.w;
    float ax = 0, ay = 0, az = 0, aw = 0;
    float ssum = 0.f;
    for (int j = beg; j < end; ++j) {
        int s = ssrc[j];
        float eh = el[(size_t)s * 4 + head] + erh;
        float w = __expf(leaky(eh) - mh);
        ssum += w;
        float4 zv = *(const float4*)(z + (size_t)s * HD0 + lane * 4);
        ax += w * zv.x; ay += w * zv.y; az += w * zv.z; aw += w * zv.w;
    }
    float inv = ssum > 0.f ? 1.f / ssum : 0.f;
    float4 b4 = *(const float4*)(bias + lane * 4);
    float4 o;
    o.x = fmaxf(ax * inv + b4.x, 0.f);
    o.y = fmaxf(ay * inv + b4.y, 0.f);
    o.z = fmaxf(az * inv + b4.z, 0.f);
    o.w = fmaxf(aw * inv + b4.w, 0.f);
    *(float4*)(hout + (size_t)d * HD0 + lane * 4) = o;
}

// Layer-1 aggregation: one wave per dst node, D=47, H=4 (188 feats; lane covers up to 3)
__global__ __launch_bounds__(64) void agg_l1(const int* __restrict__ ssrc,
        const int* __restrict__ offsets, const float* __restrict__ el,
        const float* __restrict__ er, const float* __restrict__ z,
        const float* __restrict__ bias, float* __restrict__ out) {
    int d = blockIdx.x;
    int lane = threadIdx.x;
    int beg = offsets[d], end = offsets[d + 1];
    float4 er4 = *(const float4*)(er + (size_t)d * 4);
    float m0 = -INFINITY, m1 = -INFINITY, m2 = -INFINITY, m3 = -INFINITY;
    for (int j = beg + lane; j < end; j += 64) {
        int s = ssrc[j];
        float4 e4 = *(const float4*)(el + (size_t)s * 4);
        m0 = fmaxf(m0, leaky(e4.x + er4.x));
        m1 = fmaxf(m1, leaky(e4.y + er4.y));
        m2 = fmaxf(m2, leaky(e4.z + er4.z));
        m3 = fmaxf(m3, leaky(e4.w + er4.w));
    }
#pragma unroll
    for (int off = 32; off; off >>= 1) {
        m0 = fmaxf(m0, __shfl_xor(m0, off));
        m1 = fmaxf(m1, __shfl_xor(m1, off));
        m2 = fmaxf(m2, __shfl_xor(m2, off));
        m3 = fmaxf(m3, __shfl_xor(m3, off));
    }
    const int f0 = lane, f1 = lane + 64, f2 = lane + 128;
    const int h0 = f0 / NCLS, h1 = f1 / NCLS;
    const bool has2 = f2 < HD1;
    const int h2 = has2 ? f2 / NCLS : 3;
    float a0 = 0, a1 = 0, a2 = 0;
    float s0 = 0, s1 = 0, s2 = 0, s3 = 0;
    for (int j = beg; j < end; ++j) {
        int s = ssrc[j];
        float4 e4 = *(const float4*)(el + (size_t)s * 4);
        float w0 = __expf(leaky(e4.x + er4.x) - m0);
        float w1 = __expf(leaky(e4.y + er4.y) - m1);
        float w2 = __expf(leaky(e4.z + er4.z) - m2);
        float w3 = __expf(leaky(e4.w + er4.w) - m3);
        s0 += w0; s1 += w1; s2 += w2; s3 += w3;
        const float* zr = z + (size_t)s * HD1;
        float wa = h0 == 0 ? w0 : h0 == 1 ? w1 : h0 == 2 ? w2 : w3;
        float wb = h1 == 0 ? w0 : h1 == 1 ? w1 : h1 == 2 ? w2 : w3;
        a0 += wa * zr[f0];
        a1 += wb * zr[f1];
        if (has2) {
            float wc = h2 == 0 ? w0 : h2 == 1 ? w1 : h2 == 2 ? w2 : w3;
            a2 += wc * zr[f2];
        }
    }
    float sa = h0 == 0 ? s0 : h0 == 1 ? s1 : h0 == 2 ? s2 : s3;
    float sb = h1 == 0 ? s0 : h1 == 1 ? s1 : h1 == 2 ? s2 : s3;
    float sc = h2 == 0 ? s0 : h2 == 1 ? s1 : h2 == 2 ? s2 : s3;
    float* orow = out + (size_t)d * HD1;
    orow[f0] = a0 * (sa > 0.f ? 1.f / sa : 0.f) + bias[f0];
    orow[f1] = a1 * (sb > 0.f ? 1.f / sb : 0.f) + bias[f1];
    if (has2) orow[f2] = a2 * (sc > 0.f ? 1.f / sc : 0.f) + bias[f2];
}

// mean over heads + log_softmax; one wave per node
__global__ __launch_bounds__(256) void final_k(const float* __restrict__ o1,
        float* __restrict__ y, int n) {
    int wave = threadIdx.x >> 6, lane = threadIdx.x & 63;
    int node = blockIdx.x * 4 + wave;
    if (node >= n) return;
    const float* r = o1 + (size_t)node * HD1;
    float vv = 0.f, v = -INFINITY;
    if (lane < NCLS) {
        vv = 0.25f * (r[lane] + r[lane + NCLS] + r[lane + 2 * NCLS] + r[lane + 3 * NCLS]);
        v = vv;
    }
    float mx = v;
#pragma unroll
    for (int off = 32; off; off >>= 1) mx = fmaxf(mx, __shfl_xor(mx, off));
    float p = (lane < NCLS) ? __expf(vv - mx) : 0.f;
    float sum = p;
#pragma unroll
    for (int off = 32; off; off >>= 1) sum += __shfl_xor(sum, off);
    if (lane < NCLS) y[(size_t)node * NCLS + lane] = vv - mx - logf(sum);
}

extern "C" void kernel_launch(void* const* d_in, const int* in_sizes, int n_in,
                              void* d_out, int out_size, void* d_ws, size_t ws_size,
                              hipStream_t stream) {
    const float* x    = (const float*)d_in[0];
    const int*   src0 = (const int*)d_in[1];
    const int*   dst0 = (const int*)d_in[2];
    const int*   src1 = (const int*)d_in[3];
    const int*   dst1 = (const int*)d_in[4];
    const float* W0s  = (const float*)d_in[7];
    const float* al0  = (const float*)d_in[9];
    const float* ar0  = (const float*)d_in[10];
    const float* b0   = (const float*)d_in[11];
    const float* W0d  = (const float*)d_in[8];
    const float* W1s  = (const float*)d_in[12];
    const float* W1d  = (const float*)d_in[13];
    const float* al1  = (const float*)d_in[14];
    const float* ar1  = (const float*)d_in[15];
    const float* b1   = (const float*)d_in[16];
    const int E0 = in_sizes[1], E1 = in_sizes[3];
    const int NS0 = in_sizes[0] / IN;   // 200000
    const int ND0 = 50000, ND1 = 10000; // problem constants (scalars live on device)

    char* p = (char*)d_ws;
    auto take = [&](size_t bytes) {
        char* r = p;
        p += (bytes + 255) & ~(size_t)255;
        return r;
    };
    float* z0  = (float*)take((size_t)NS0 * HD0 * 4);
    float* h   = (float*)take((size_t)ND0 * HD0 * 4);
    float* z1  = (float*)take((size_t)ND0 * HD1 * 4);
    float* o1  = (float*)take((size_t)ND1 * HD1 * 4);
    float* el0 = (float*)take((size_t)NS0 * 4 * 4);
    float* er0 = (float*)take((size_t)ND0 * 4 * 4);
    float* el1 = (float*)take((size_t)ND0 * 4 * 4);
    float* er1 = (float*)take((size_t)ND1 * 4 * 4);
    float* vl0 = (float*)take(IN * 4 * 4);
    float* vr0 = (float*)take(IN * 4 * 4);
    float* vl1 = (float*)take(IN * 4 * 4);
    float* vr1 = (float*)take(IN * 4 * 4);
    int* counts0 = (int*)take((size_t)ND0 * 4);
    int* offs0   = (int*)take((size_t)(ND0 + 1) * 4);
    int* cur0    = (int*)take((size_t)ND0 * 4);
    int* ss0     = (int*)take((size_t)E0 * 4);
    int* counts1 = (int*)take((size_t)ND1 * 4);
    int* offs1   = (int*)take((size_t)(ND1 + 1) * 4);
    int* cur1    = (int*)take((size_t)ND1 * 4);
    int* ss1     = (int*)take((size_t)E1 * 4);

    hipMemsetAsync(counts0, 0, (size_t)ND0 * 4, stream);
    hipMemsetAsync(counts1, 0, (size_t)ND1 * 4, stream);

    make_v<<<(IN * HEADS + 255) / 256, 256, 0, stream>>>(W0s, al0, vl0, HID);
    make_v<<<(IN * HEADS + 255) / 256, 256, 0, stream>>>(W0d, ar0, vr0, HID);
    make_v<<<(IN * HEADS + 255) / 256, 256, 0, stream>>>(W1s, al1, vl1, NCLS);
    make_v<<<(IN * HEADS + 255) / 256, 256, 0, stream>>>(W1d, ar1, vr1, NCLS);

    // ---- layer 0 ----
    gemm_f32<HD0><<<(NS0 + 63) / 64, 256, 0, stream>>>(x, W0s, z0, NS0);
    gemv_lr<<<(NS0 + 3) / 4, 256, 0, stream>>>(x, vl0, vr0, el0, er0, NS0, ND0);
    hist_k<<<(E0 + 255) / 256, 256, 0, stream>>>(dst0, E0, counts0);
    scan_k<<<1, 1024, 0, stream>>>(counts0, ND0, offs0, cur0);
    scatter_k<<<(E0 + 255) / 256, 256, 0, stream>>>(src0, dst0, E0, cur0, ss0);
    agg_l0<<<ND0, 64, 0, stream>>>(ss0, offs0, el0, er0, z0, b0, h);

    // ---- layer 1 ----
    gemm_f32<HD1><<<(ND0 + 63) / 64, 256, 0, stream>>>(h, W1s, z1, ND0);
    gemv_lr<<<(ND0 + 3) / 4, 256, 0, stream>>>(h, vl1, vr1, el1, er1, ND0, ND1);
    hist_k<<<(E1 + 255) / 256, 256, 0, stream>>>(dst1, E1, counts1);
    scan_k<<<1, 1024, 0, stream>>>(counts1, ND1, offs1, cur1);
    scatter_k<<<(E1 + 255) / 256, 256, 0, stream>>>(src1, dst1, E1, cur1, ss1);
    agg_l1<<<ND1, 64, 0, stream>>>(ss1, offs1, el1, er1, z1, b1, o1);

    final_k<<<(ND1 + 3) / 4, 256, 0, stream>>>(o1, (float*)d_out, ND1);
}

// Round 2
// 476.431 us; speedup vs baseline: 1.9768x; 1.9768x over previous
//
#include <hip/hip_runtime.h>
#include <math.h>

typedef _Float16 half8 __attribute__((ext_vector_type(8)));
typedef _Float16 half4 __attribute__((ext_vector_type(4)));
typedef float f32x4 __attribute__((ext_vector_type(4)));

constexpr int IN    = 256;
constexpr int HEADS = 4;
constexpr int HID   = 64;
constexpr int NCLS  = 47;
constexpr int HD0   = 256;
constexpr int HD1   = 188;
constexpr float NEG_SLOPE = 0.2f;
constexpr int ND0 = 50000, ND1 = 10000;

static __device__ __forceinline__ float leaky(float x) {
    return x >= 0.f ? x : NEG_SLOPE * x;
}

// vT[h*IN + k] = sum_d W[k, h*D+d] * attn[h,d]
__global__ void make_vT(const float* __restrict__ W, const float* __restrict__ attn,
                        float* __restrict__ vT, int D) {
    int id = blockIdx.x * blockDim.x + threadIdx.x;
    if (id >= IN * HEADS) return;
    int k = id >> 2, h = id & 3;
    const float* wr = W + (size_t)k * (HEADS * D) + h * D;
    const float* ar = attn + h * D;
    float s = 0.f;
    for (int d = 0; d < D; ++d) s += wr[d] * ar[d];
    vT[h * IN + k] = s;
}

// Bt[n][k] = (n < N) ? (f16)W[k*N+n] : 0 ;  Bt is [BNp][IN]
__global__ void cvtB(const float* __restrict__ W, _Float16* __restrict__ Bt, int N, int BNp) {
    int id = blockIdx.x * 256 + threadIdx.x;
    if (id >= BNp * IN) return;
    int n = id / IN, k = id % IN;
    Bt[id] = (n < N) ? (_Float16)W[(size_t)k * N + n] : (_Float16)0.f;
}

// MFMA GEMM: Z[M, NOUT] = A[M,256] @ Bt^T ; Bt is [BN][256] f16 (col-major weights).
// BM=128, BK=32, 512 threads = 8 waves (2M x 4N). Optional fused el = Z . attn_l (per head).
template <int BN, int NOUT, bool AHALF, bool ZHALF, bool FUSE_EL>
__global__ __launch_bounds__(512) void gemm_mfma(const void* __restrict__ Av,
        const _Float16* __restrict__ Bt, void* __restrict__ Z,
        const float* __restrict__ attn_l, float* __restrict__ el, int M) {
    constexpr int FN = BN / 64;              // N-frags per wave
    __shared__ __align__(16) _Float16 As[128 * 40];
    __shared__ __align__(16) _Float16 Bs[BN * 40];
    const int t  = threadIdx.x;
    const int l  = t & 63, w = t >> 6;
    const int wm = w >> 2, wn = w & 3;
    const int lr = l & 15, lh = l >> 4;
    const int bm = blockIdx.x * 128;

    f32x4 zero = {0.f, 0.f, 0.f, 0.f};
    f32x4 acc[4][FN];
#pragma unroll
    for (int mi = 0; mi < 4; ++mi)
#pragma unroll
        for (int nj = 0; nj < FN; ++nj) acc[mi][nj] = zero;

    const int ar_ = t >> 2;          // A row 0..127
    const int ak_ = (t & 3) * 8;     // A k-group
    const int bc_ = t >> 1;          // B col 0..255
    const int bk_ = (t & 1) * 16;    // B k-group

    for (int k0 = 0; k0 < IN; k0 += 32) {
        {   // stage A (convert fp32->f16 if needed)
            int grow = bm + ar_;
            half8 av;
            if (grow < M) {
                if constexpr (AHALF) {
                    const _Float16* Ah = (const _Float16*)Av;
                    av = *(const half8*)(Ah + (size_t)grow * IN + k0 + ak_);
                } else {
                    const float* Af = (const float*)Av;
                    const float* p = Af + (size_t)grow * IN + k0 + ak_;
                    float4 f0 = *(const float4*)p;
                    float4 f1 = *(const float4*)(p + 4);
                    av[0] = (_Float16)f0.x; av[1] = (_Float16)f0.y;
                    av[2] = (_Float16)f0.z; av[3] = (_Float16)f0.w;
                    av[4] = (_Float16)f1.x; av[5] = (_Float16)f1.y;
                    av[6] = (_Float16)f1.z; av[7] = (_Float16)f1.w;
                }
            } else {
#pragma unroll
                for (int i = 0; i < 8; ++i) av[i] = (_Float16)0.f;
            }
            *(half8*)&As[ar_ * 40 + ak_] = av;
        }
        if (bc_ < BN) {  // stage B (already f16, [col][k] layout)
            const _Float16* p = Bt + (size_t)bc_ * IN + k0 + bk_;
            *(half8*)&Bs[bc_ * 40 + bk_]     = *(const half8*)p;
            *(half8*)&Bs[bc_ * 40 + bk_ + 8] = *(const half8*)(p + 8);
        }
        __syncthreads();
        half8 af[4], bf[FN];
#pragma unroll
        for (int mi = 0; mi < 4; ++mi)
            af[mi] = *(const half8*)&As[(wm * 64 + mi * 16 + lr) * 40 + lh * 8];
#pragma unroll
        for (int nj = 0; nj < FN; ++nj)
            bf[nj] = *(const half8*)&Bs[(wn * (16 * FN) + nj * 16 + lr) * 40 + lh * 8];
#pragma unroll
        for (int mi = 0; mi < 4; ++mi)
#pragma unroll
            for (int nj = 0; nj < FN; ++nj)
                acc[mi][nj] = __builtin_amdgcn_mfma_f32_16x16x32_f16(
                    af[mi], bf[nj], acc[mi][nj], 0, 0, 0);
        __syncthreads();
    }
    // write Z (D layout: row=(l>>4)*4+r, col=l&15)
#pragma unroll
    for (int mi = 0; mi < 4; ++mi) {
#pragma unroll
        for (int r = 0; r < 4; ++r) {
            int grow = bm + wm * 64 + mi * 16 + lh * 4 + r;
            if (grow < M) {
#pragma unroll
                for (int nj = 0; nj < FN; ++nj) {
                    int col = wn * (16 * FN) + nj * 16 + lr;
                    if (col < NOUT) {
                        if constexpr (ZHALF)
                            ((_Float16*)Z)[(size_t)grow * NOUT + col] = (_Float16)acc[mi][nj][r];
                        else
                            ((float*)Z)[(size_t)grow * NOUT + col] = acc[mi][nj][r];
                    }
                }
            }
        }
    }
    if constexpr (FUSE_EL) {
        // wave wn owns head wn's 64 columns exactly (BN==256, HID==64)
        float alv[FN];
#pragma unroll
        for (int nj = 0; nj < FN; ++nj) alv[nj] = attn_l[wn * (16 * FN) + nj * 16 + lr];
#pragma unroll
        for (int mi = 0; mi < 4; ++mi) {
#pragma unroll
            for (int r = 0; r < 4; ++r) {
                float s = 0.f;
#pragma unroll
                for (int nj = 0; nj < FN; ++nj) s += acc[mi][nj][r] * alv[nj];
                s += __shfl_xor(s, 1); s += __shfl_xor(s, 2);
                s += __shfl_xor(s, 4); s += __shfl_xor(s, 8);
                int grow = bm + wm * 64 + mi * 16 + lh * 4 + r;
                if (lr == 0 && grow < M) el[(size_t)grow * 4 + wn] = s;
            }
        }
    }
}

// er[m,h] = x[m,:] @ vrT[h,:]  (fp32 A); one wave per row
__global__ __launch_bounds__(256) void gemv_er_f32(const float* __restrict__ A,
        const float* __restrict__ vrT, float* __restrict__ er, int M) {
    int wv = threadIdx.x >> 6, lane = threadIdx.x & 63;
    int row = blockIdx.x * 4 + wv;
    if (row >= M) return;
    float4 xa = *(const float4*)(A + (size_t)row * IN + lane * 4);
    float s[4];
#pragma unroll
    for (int h = 0; h < 4; ++h) {
        float4 v = *(const float4*)(vrT + h * IN + lane * 4);
        s[h] = xa.x * v.x + xa.y * v.y + xa.z * v.z + xa.w * v.w;
    }
#pragma unroll
    for (int off = 32; off; off >>= 1)
#pragma unroll
        for (int h = 0; h < 4; ++h) s[h] += __shfl_xor(s[h], off);
    if (lane == 0) *(float4*)(er + (size_t)row * 4) = make_float4(s[0], s[1], s[2], s[3]);
}

// el/er from f16 A; el for all rows, er for rows < Mr
__global__ __launch_bounds__(256) void gemv_lr_f16(const _Float16* __restrict__ A,
        const float* __restrict__ vlT, const float* __restrict__ vrT,
        float* __restrict__ el, float* __restrict__ er, int M, int Mr) {
    int wv = threadIdx.x >> 6, lane = threadIdx.x & 63;
    int row = blockIdx.x * 4 + wv;
    if (row >= M) return;
    half4 ah = *(const half4*)(A + (size_t)row * IN + lane * 4);
    float a0 = (float)ah[0], a1 = (float)ah[1], a2 = (float)ah[2], a3 = (float)ah[3];
    float sl[4], sr[4];
#pragma unroll
    for (int h = 0; h < 4; ++h) {
        float4 v = *(const float4*)(vlT + h * IN + lane * 4);
        sl[h] = a0 * v.x + a1 * v.y + a2 * v.z + a3 * v.w;
        float4 u = *(const float4*)(vrT + h * IN + lane * 4);
        sr[h] = a0 * u.x + a1 * u.y + a2 * u.z + a3 * u.w;
    }
#pragma unroll
    for (int off = 32; off; off >>= 1)
#pragma unroll
        for (int h = 0; h < 4; ++h) {
            sl[h] += __shfl_xor(sl[h], off);
            sr[h] += __shfl_xor(sr[h], off);
        }
    if (lane == 0) {
        *(float4*)(el + (size_t)row * 4) = make_float4(sl[0], sl[1], sl[2], sl[3]);
        if (row < Mr)
            *(float4*)(er + (size_t)row * 4) = make_float4(sr[0], sr[1], sr[2], sr[3]);
    }
}

__global__ void hist_k(const int* __restrict__ dst, int E, int* __restrict__ counts) {
    int i = blockIdx.x * blockDim.x + threadIdx.x;
    if (i < E) atomicAdd(&counts[dst[i]], 1);
}

__global__ __launch_bounds__(1024) void scan_k(const int* __restrict__ counts, int n,
        int* __restrict__ offsets, int* __restrict__ cursor) {
    __shared__ int part[1024];
    int tid = threadIdx.x;
    int chunk = (n + 1023) >> 10;
    int b = tid * chunk, e = min(b + chunk, n);
    int s = 0;
    for (int i = b; i < e; ++i) s += counts[i];
    part[tid] = s;
    __syncthreads();
    if (tid == 0) {
        int run = 0;
        for (int i = 0; i < 1024; ++i) { int t = part[i]; part[i] = run; run += t; }
        offsets[n] = run;
    }
    __syncthreads();
    int run = part[tid];
    for (int i = b; i < e; ++i) {
        int c = counts[i];
        offsets[i] = run;
        cursor[i] = run;
        run += c;
    }
}

__global__ void scatter_k(const int* __restrict__ src, const int* __restrict__ dst, int E,
        int* __restrict__ cursor, int* __restrict__ ssrc) {
    int i = blockIdx.x * blockDim.x + threadIdx.x;
    if (i < E) {
        int p = atomicAdd(&cursor[dst[i]], 1);
        ssrc[p] = src[i];
    }
}

// Layer-0 aggregation, single pass (no segment max): z f16, out h f16 (relu + bias)
__global__ __launch_bounds__(64) void agg_l0(const int* __restrict__ ssrc,
        const int* __restrict__ offs, const float* __restrict__ el,
        const float* __restrict__ er, const _Float16* __restrict__ z,
        const float* __restrict__ bias, _Float16* __restrict__ h) {
    int d = blockIdx.x, lane = threadIdx.x, head = lane >> 4;
    int beg = offs[d], end = offs[d + 1];
    float erh = er[(size_t)d * 4 + head];
    float ax = 0, ay = 0, az = 0, aw = 0, ssum = 0;
    for (int j = beg; j < end; ++j) {
        int s = ssrc[j];
        float e = el[(size_t)s * 4 + head] + erh;
        float wgt = __expf(leaky(e));
        ssum += wgt;
        half4 zv = *(const half4*)(z + (size_t)s * HD0 + lane * 4);
        ax += wgt * (float)zv[0]; ay += wgt * (float)zv[1];
        az += wgt * (float)zv[2]; aw += wgt * (float)zv[3];
    }
    float inv = ssum > 0.f ? 1.f / ssum : 0.f;
    const float* b = bias + lane * 4;
    half4 o;
    o[0] = (_Float16)fmaxf(ax * inv + b[0], 0.f);
    o[1] = (_Float16)fmaxf(ay * inv + b[1], 0.f);
    o[2] = (_Float16)fmaxf(az * inv + b[2], 0.f);
    o[3] = (_Float16)fmaxf(aw * inv + b[3], 0.f);
    *(half4*)(h + (size_t)d * HD0 + lane * 4) = o;
}

// Layer-1 aggregation, single pass: z f32 [*,188], out o1 f32 (+bias)
__global__ __launch_bounds__(64) void agg_l1(const int* __restrict__ ssrc,
        const int* __restrict__ offs, const float* __restrict__ el,
        const float* __restrict__ er, const float* __restrict__ z,
        const float* __restrict__ bias, float* __restrict__ out) {
    int d = blockIdx.x, lane = threadIdx.x;
    int beg = offs[d], end = offs[d + 1];
    float4 er4 = *(const float4*)(er + (size_t)d * 4);
    const int f0 = lane, f1 = lane + 64, f2 = lane + 128;
    const int h0 = f0 / NCLS, h1 = f1 / NCLS;
    const bool has2 = f2 < HD1;
    const int h2 = has2 ? f2 / NCLS : 3;
    float a0 = 0, a1 = 0, a2 = 0;
    float s0 = 0, s1 = 0, s2 = 0, s3 = 0;
    for (int j = beg; j < end; ++j) {
        int s = ssrc[j];
        float4 e4 = *(const float4*)(el + (size_t)s * 4);
        float w0 = __expf(leaky(e4.x + er4.x));
        float w1 = __expf(leaky(e4.y + er4.y));
        float w2 = __expf(leaky(e4.z + er4.z));
        float w3 = __expf(leaky(e4.w + er4.w));
        s0 += w0; s1 += w1; s2 += w2; s3 += w3;
        const float* zr = z + (size_t)s * HD1;
        a0 += (h0 == 0 ? w0 : h0 == 1 ? w1 : h0 == 2 ? w2 : w3) * zr[f0];
        a1 += (h1 == 0 ? w0 : h1 == 1 ? w1 : h1 == 2 ? w2 : w3) * zr[f1];
        if (has2) a2 += (h2 == 0 ? w0 : h2 == 1 ? w1 : h2 == 2 ? w2 : w3) * zr[f2];
    }
    float sa = h0 == 0 ? s0 : h0 == 1 ? s1 : h0 == 2 ? s2 : s3;
    float sb = h1 == 0 ? s0 : h1 == 1 ? s1 : h1 == 2 ? s2 : s3;
    float sc = h2 == 0 ? s0 : h2 == 1 ? s1 : h2 == 2 ? s2 : s3;
    float* orow = out + (size_t)d * HD1;
    orow[f0] = a0 * (sa > 0.f ? 1.f / sa : 0.f) + bias[f0];
    orow[f1] = a1 * (sb > 0.f ? 1.f / sb : 0.f) + bias[f1];
    if (has2) orow[f2] = a2 * (sc > 0.f ? 1.f / sc : 0.f) + bias[f2];
}

// mean over heads + log_softmax; one wave per node
__global__ __launch_bounds__(256) void final_k(const float* __restrict__ o1,
        float* __restrict__ y, int n) {
    int wave = threadIdx.x >> 6, lane = threadIdx.x & 63;
    int node = blockIdx.x * 4 + wave;
    if (node >= n) return;
    const float* r = o1 + (size_t)node * HD1;
    float vv = 0.f, v = -INFINITY;
    if (lane < NCLS) {
        vv = 0.25f * (r[lane] + r[lane + NCLS] + r[lane + 2 * NCLS] + r[lane + 3 * NCLS]);
        v = vv;
    }
    float mx = v;
#pragma unroll
    for (int off = 32; off; off >>= 1) mx = fmaxf(mx, __shfl_xor(mx, off));
    float p = (lane < NCLS) ? __expf(vv - mx) : 0.f;
    float sum = p;
#pragma unroll
    for (int off = 32; off; off >>= 1) sum += __shfl_xor(sum, off);
    if (lane < NCLS) y[(size_t)node * NCLS + lane] = vv - mx - logf(sum);
}

extern "C" void kernel_launch(void* const* d_in, const int* in_sizes, int n_in,
                              void* d_out, int out_size, void* d_ws, size_t ws_size,
                              hipStream_t stream) {
    const float* x    = (const float*)d_in[0];
    const int*   src0 = (const int*)d_in[1];
    const int*   dst0 = (const int*)d_in[2];
    const int*   src1 = (const int*)d_in[3];
    const int*   dst1 = (const int*)d_in[4];
    const float* W0s  = (const float*)d_in[7];
    const float* W0d  = (const float*)d_in[8];
    const float* al0  = (const float*)d_in[9];
    const float* ar0  = (const float*)d_in[10];
    const float* b0   = (const float*)d_in[11];
    const float* W1s  = (const float*)d_in[12];
    const float* W1d  = (const float*)d_in[13];
    const float* al1  = (const float*)d_in[14];
    const float* ar1  = (const float*)d_in[15];
    const float* b1   = (const float*)d_in[16];
    const int E0 = in_sizes[1], E1 = in_sizes[3];
    const int NS0 = in_sizes[0] / IN;   // 200000

    char* p = (char*)d_ws;
    auto take = [&](size_t bytes) {
        char* r = p;
        p += (bytes + 255) & ~(size_t)255;
        return r;
    };
    _Float16* z0  = (_Float16*)take((size_t)NS0 * HD0 * 2);
    _Float16* h   = (_Float16*)take((size_t)ND0 * HD0 * 2);
    float*    z1  = (float*)take((size_t)ND0 * HD1 * 4);
    float*    o1  = (float*)take((size_t)ND1 * HD1 * 4);
    float*    el0 = (float*)take((size_t)NS0 * 4 * 4);
    float*    er0 = (float*)take((size_t)ND0 * 4 * 4);
    float*    el1 = (float*)take((size_t)ND0 * 4 * 4);
    float*    er1 = (float*)take((size_t)ND1 * 4 * 4);
    _Float16* B0t = (_Float16*)take((size_t)256 * IN * 2);
    _Float16* B1t = (_Float16*)take((size_t)192 * IN * 2);
    float*    vr0T = (float*)take(4 * IN * 4);
    float*    vl1T = (float*)take(4 * IN * 4);
    float*    vr1T = (float*)take(4 * IN * 4);
    int* counts0 = (int*)take((size_t)ND0 * 4);
    int* offs0   = (int*)take((size_t)(ND0 + 1) * 4);
    int* cur0    = (int*)take((size_t)ND0 * 4);
    int* ss0     = (int*)take((size_t)E0 * 4);
    int* counts1 = (int*)take((size_t)ND1 * 4);
    int* offs1   = (int*)take((size_t)(ND1 + 1) * 4);
    int* cur1    = (int*)take((size_t)ND1 * 4);
    int* ss1     = (int*)take((size_t)E1 * 4);

    hipMemsetAsync(counts0, 0, (size_t)ND0 * 4, stream);
    hipMemsetAsync(counts1, 0, (size_t)ND1 * 4, stream);

    // prep: folded attention vectors + f16 transposed weights
    make_vT<<<4, 256, 0, stream>>>(W0d, ar0, vr0T, HID);
    make_vT<<<4, 256, 0, stream>>>(W1s, al1, vl1T, NCLS);
    make_vT<<<4, 256, 0, stream>>>(W1d, ar1, vr1T, NCLS);
    cvtB<<<(256 * IN + 255) / 256, 256, 0, stream>>>(W0s, B0t, HD0, 256);
    cvtB<<<(192 * IN + 255) / 256, 256, 0, stream>>>(W1s, B1t, HD1, 192);

    // ---- layer 0 ----
    gemm_mfma<256, 256, false, true, true><<<(NS0 + 127) / 128, 512, 0, stream>>>(
        (const void*)x, B0t, (void*)z0, al0, el0, NS0);
    gemv_er_f32<<<(ND0 + 3) / 4, 256, 0, stream>>>(x, vr0T, er0, ND0);
    hist_k<<<(E0 + 255) / 256, 256, 0, stream>>>(dst0, E0, counts0);
    scan_k<<<1, 1024, 0, stream>>>(counts0, ND0, offs0, cur0);
    scatter_k<<<(E0 + 255) / 256, 256, 0, stream>>>(src0, dst0, E0, cur0, ss0);
    agg_l0<<<ND0, 64, 0, stream>>>(ss0, offs0, el0, er0, z0, b0, h);

    // ---- layer 1 ----
    gemm_mfma<192, 188, true, false, false><<<(ND0 + 127) / 128, 512, 0, stream>>>(
        (const void*)h, B1t, (void*)z1, nullptr, nullptr, ND0);
    gemv_lr_f16<<<(ND0 + 3) / 4, 256, 0, stream>>>(h, vl1T, vr1T, el1, er1, ND0, ND1);
    hist_k<<<(E1 + 255) / 256, 256, 0, stream>>>(dst1, E1, counts1);
    scan_k<<<1, 1024, 0, stream>>>(counts1, ND1, offs1, cur1);
    scatter_k<<<(E1 + 255) / 256, 256, 0, stream>>>(src1, dst1, E1, cur1, ss1);
    agg_l1<<<ND1, 64, 0, stream>>>(ss1, offs1, el1, er1, z1, b1, o1);

    final_k<<<(ND1 + 3) / 4, 256, 0, stream>>>(o1, (float*)d_out, ND1);
}